// Round 10
// baseline (422.252 us; speedup 1.0000x reference)
//
#include <hip/hip_runtime.h>
#include <math.h>

#define S_LEN 2048
#define D_MODEL 1024
#define NH 16
#define DK 64
#define BATCH 4

// log2(10000)/64
#define ROPE_L2F 0.20762050593046014f
// 0.125 * log2(e): folds 1/sqrt(dk) and exp->exp2 conversion into Q
#define QSCALE 0.18033688011112042f

typedef __attribute__((ext_vector_type(8))) short bf16x8;
typedef __attribute__((ext_vector_type(4))) short short4v;
typedef __attribute__((ext_vector_type(4))) float f32x4;

__device__ inline short f2bf(float f) {            // RNE fp32 -> bf16 bits
    unsigned u = __builtin_bit_cast(unsigned, f);
    unsigned r = u + 0x7FFFu + ((u >> 16) & 1u);
    return (short)(r >> 16);
}

// async global->LDS, 16B per lane; lds base must be wave-uniform.
__device__ inline void load_lds16(const void* g, void* l) {
    __builtin_amdgcn_global_load_lds(
        (const __attribute__((address_space(1))) unsigned int*)g,
        (__attribute__((address_space(3))) unsigned int*)l, 16, 0, 0);
}

// ---------------------------------------------------------------------------
// One-time fp32 -> bf16 conversions.
// ---------------------------------------------------------------------------
__global__ __launch_bounds__(256) void conv_bf16(
    const float* __restrict__ src, short* __restrict__ dst, int n)
{
    int i = (blockIdx.x * 256 + threadIdx.x) * 8;
    if (i >= n) return;
    float4 a = *(const float4*)&src[i];
    float4 b = *(const float4*)&src[i + 4];
    short h[8] = { f2bf(a.x), f2bf(a.y), f2bf(a.z), f2bf(a.w),
                   f2bf(b.x), f2bf(b.y), f2bf(b.z), f2bf(b.w) };
    *(bf16x8*)&dst[i] = *(bf16x8*)h;
}

__global__ __launch_bounds__(256) void conv_w4(
    const float* __restrict__ Wq, const float* __restrict__ Wk,
    const float* __restrict__ Wv, const float* __restrict__ Wo,
    short* __restrict__ dst)
{
    const float* srcs[4] = { Wq, Wk, Wv, Wo };
    const float* s = srcs[blockIdx.y];
    short* d = dst + (size_t)blockIdx.y * (D_MODEL * D_MODEL);
    int i = (blockIdx.x * 256 + threadIdx.x) * 8;
    float4 a = *(const float4*)&s[i];
    float4 b = *(const float4*)&s[i + 4];
    short h[8] = { f2bf(a.x), f2bf(a.y), f2bf(a.z), f2bf(a.w),
                   f2bf(b.x), f2bf(b.y), f2bf(b.z), f2bf(b.w) };
    *(bf16x8*)&d[i] = *(bf16x8*)h;
}

// ---------------------------------------------------------------------------
// Fused QKV projection, BK=64, global_load_lds staging, 8-chunk XOR swizzle.
// Grid (24, 64): which = bx>>3 (0=Q,1=K,2=V), n0 = (bx&7)*128.
// Rows of 64 shorts = 128 B = 8 chunks; phys chunk = logical ^ (row&7):
// frag b128 reads spread all 32 banks 2-way (free).
// Q/K epilogue: RoPE*scale -> bf16 (b,h,s,dk). V: bf16 V^T (b*NH*DK, S)
// via wave-private LDS transpose (tsc unioned with As/Bs).
// ---------------------------------------------------------------------------
__global__ __launch_bounds__(256) void proj_qkv(
    const short* __restrict__ X, const short* __restrict__ Wqkv,
    const int* __restrict__ tp, short* __restrict__ Qo,
    short* __restrict__ Ko, short* __restrict__ Vto)
{
    __shared__ char smem[36864];
    short (*As)[64] = (short(*)[64])smem;
    short (*Bs)[64] = (short(*)[64])(smem + 16384);

    const int bx = blockIdx.x;
    const int which = bx >> 3;
    const int n0 = (bx & 7) * 128;
    const int m0 = blockIdx.y * 128;
    const int tid = threadIdx.x;
    const int lane = tid & 63;
    const int wave = tid >> 6;
    const int quad = lane >> 4;
    const int l16 = lane & 15;
    const int wr = (wave >> 1) * 64;
    const int wc = (wave & 1) * 64;

    const short* A = X;
    const short* Bw = Wqkv + (size_t)which * (D_MODEL * D_MODEL);

    // staging geometry: per call 8 rows x 8 chunks; lane -> (row lane>>3,
    // phys chunk lane&7) in LDS; fetch logical chunk (lane&7)^(lane>>3).
    const int srw = lane >> 3;
    const int sl = (lane & 7) ^ srw;
    const short* ag[4];
    const short* bg[4];
#pragma unroll
    for (int j = 0; j < 4; ++j) {
        ag[j] = &A[(size_t)(m0 + wave * 32 + j * 8 + srw) * D_MODEL + sl * 8];
        bg[j] = &Bw[(size_t)(n0 + wave * 32 + j * 8 + srw) * D_MODEL + sl * 8];
    }

    f32x4 acc[4][4] = {};

    for (int k0 = 0; k0 < D_MODEL; k0 += 64) {
#pragma unroll
        for (int j = 0; j < 4; ++j) {
            load_lds16(ag[j], &As[wave * 32 + j * 8][0]);
            load_lds16(bg[j], &Bs[wave * 32 + j * 8][0]);
            ag[j] += 64; bg[j] += 64;
        }
        __syncthreads();

#pragma unroll
        for (int c = 0; c < 2; ++c) {
            const int pc = ((c * 4 + quad) ^ (l16 & 7)) * 8;
            bf16x8 a_h[4], b_h[4];
#pragma unroll
            for (int t = 0; t < 4; ++t) {
                a_h[t] = *(const bf16x8*)&As[wr + t * 16 + l16][pc];
                b_h[t] = *(const bf16x8*)&Bs[wc + t * 16 + l16][pc];
            }
#pragma unroll
            for (int mt = 0; mt < 4; ++mt)
#pragma unroll
                for (int nt = 0; nt < 4; ++nt)
                    acc[mt][nt] = __builtin_amdgcn_mfma_f32_16x16x32_bf16(
                        a_h[mt], b_h[nt], acc[mt][nt], 0, 0, 0);
        }
        __syncthreads();
    }

    if (which == 2) {
        // V^T epilogue: wave-private transpose (tsc aliases As/Bs; all LDS
        // reads done, loop ended at a barrier; tsc region is wave-private).
        short (*tsc)[64][72] = (short(*)[64][72])smem;
#pragma unroll
        for (int mt = 0; mt < 4; ++mt)
#pragma unroll
            for (int nt = 0; nt < 4; ++nt)
#pragma unroll
                for (int r = 0; r < 4; ++r)
                    tsc[wave][nt * 16 + l16][mt * 16 + quad * 4 + r] =
                        f2bf(acc[mt][nt][r]);
        const int f = n0 + wc + lane;
        const int head = f >> 6;
        const int d = f & 63;
        const int row0 = m0 + wr;
        const int bi = row0 >> 11;
        const int si0 = row0 & (S_LEN - 1);
        short* dst = &Vto[(((size_t)bi * NH + head) * DK + d) * S_LEN + si0];
#pragma unroll
        for (int j = 0; j < 8; ++j)
            *(bf16x8*)&dst[j * 8] = *(const bf16x8*)&tsc[wave][lane][j * 8];
        return;
    }

    short* outh = (which == 0) ? Qo : Ko;
    const float scale = (which == 0) ? QSCALE : 1.0f;
#pragma unroll
    for (int mt = 0; mt < 4; ++mt) {
#pragma unroll
        for (int r = 0; r < 4; ++r) {
            const int row = m0 + wr + mt * 16 + quad * 4 + r;
            const int bi = row >> 11;
            const int si = row & (S_LEN - 1);
            float pos = (float)tp[si];
#pragma unroll
            for (int nt = 0; nt < 4; ++nt) {
                int col = n0 + wc + nt * 16 + l16;
                int head = col >> 6;
                int tloc = col & 63;
                float v = acc[mt][nt][r];
                float partner = __shfl_xor(v, 1);
                int tb = tloc & ~1;
                float xe = (lane & 1) ? partner : v;
                float xo = (lane & 1) ? v : partner;
                float freq = exp2f(-(float)tb * ROPE_L2F);
                float ang = pos * freq;
                float s, c;
                __sincosf(ang, &s, &c);
                float res = ((lane & 1) ? (s * xe + c * xo)
                                        : (c * xe - s * xo)) * scale;
                outh[(((size_t)bi * NH + head) * S_LEN + si) * DK + tloc] =
                    f2bf(res);
            }
        }
    }
}

// ---------------------------------------------------------------------------
// Output projection (Wo), BK=64 core, fp32 row-major out.
// ---------------------------------------------------------------------------
__global__ __launch_bounds__(256) void proj_out(
    const short* __restrict__ A, const short* __restrict__ Bw,
    float* __restrict__ outf)
{
    __shared__ short As[128][64];
    __shared__ short Bs[128][64];

    const int m0 = blockIdx.y * 128;
    const int n0 = blockIdx.x * 128;
    const int tid = threadIdx.x;
    const int lane = tid & 63;
    const int wave = tid >> 6;
    const int quad = lane >> 4;
    const int l16 = lane & 15;
    const int wr = (wave >> 1) * 64;
    const int wc = (wave & 1) * 64;

    const int srw = lane >> 3;
    const int sl = (lane & 7) ^ srw;
    const short* ag[4];
    const short* bg[4];
#pragma unroll
    for (int j = 0; j < 4; ++j) {
        ag[j] = &A[(size_t)(m0 + wave * 32 + j * 8 + srw) * D_MODEL + sl * 8];
        bg[j] = &Bw[(size_t)(n0 + wave * 32 + j * 8 + srw) * D_MODEL + sl * 8];
    }

    f32x4 acc[4][4] = {};

    for (int k0 = 0; k0 < D_MODEL; k0 += 64) {
#pragma unroll
        for (int j = 0; j < 4; ++j) {
            load_lds16(ag[j], &As[wave * 32 + j * 8][0]);
            load_lds16(bg[j], &Bs[wave * 32 + j * 8][0]);
            ag[j] += 64; bg[j] += 64;
        }
        __syncthreads();

#pragma unroll
        for (int c = 0; c < 2; ++c) {
            const int pc = ((c * 4 + quad) ^ (l16 & 7)) * 8;
            bf16x8 a_h[4], b_h[4];
#pragma unroll
            for (int t = 0; t < 4; ++t) {
                a_h[t] = *(const bf16x8*)&As[wr + t * 16 + l16][pc];
                b_h[t] = *(const bf16x8*)&Bs[wc + t * 16 + l16][pc];
            }
#pragma unroll
            for (int mt = 0; mt < 4; ++mt)
#pragma unroll
                for (int nt = 0; nt < 4; ++nt)
                    acc[mt][nt] = __builtin_amdgcn_mfma_f32_16x16x32_bf16(
                        a_h[mt], b_h[nt], acc[mt][nt], 0, 0, 0);
        }
        __syncthreads();
    }

#pragma unroll
    for (int mt = 0; mt < 4; ++mt)
#pragma unroll
        for (int r = 0; r < 4; ++r) {
            const int row = m0 + wr + mt * 16 + quad * 4 + r;
#pragma unroll
            for (int nt = 0; nt < 4; ++nt) {
                int col = n0 + wc + nt * 16 + l16;
                outf[(size_t)row * D_MODEL + col] = acc[mt][nt][r];
            }
        }
}

// ---------------------------------------------------------------------------
// MFMA flash causal attention — split-K over waves, pipelined.
// Block = 32 q rows; wave w handles k-tiles t = w, w+4, ... (m=0 softmax is
// exact & associative). K/V prefetch for t+4 issues into the SAME registers
// right after their last use (WAR-enforced software pipeline, no copies).
// Ps (k-loop) and Ob/lb (combine) share one LDS allocation (union) with a
// barrier between the two phases: 34.3 KB -> 4 blocks/CU.
// ---------------------------------------------------------------------------
__global__ __launch_bounds__(256) void attn_bf16(
    const short* __restrict__ Q, const short* __restrict__ K,
    const short* __restrict__ Vt, short* __restrict__ O)
{
    __shared__ char smem[34304];
    short (*Ps)[72] = (short(*)[72])smem;            // [128][72] (loop phase)
    float (*Ob)[32][66] = (float(*)[32][66])smem;    // [4][32][66] (combine)
    float* lb = (float*)(smem + 33792);              // [4*32]

    const int bh = blockIdx.y;
    const int bx = (gridDim.x - 1) - blockIdx.x;     // heavy blocks first
    const int q0 = bx * 32;
    const int tid = threadIdx.x;
    const int wave = tid >> 6;
    const int lane = tid & 63;
    const int quad = lane >> 4;
    const int l16 = lane & 15;

    const short* Kb  = K  + (size_t)bh * S_LEN * DK;
    const short* Vtb = Vt + (size_t)bh * DK * S_LEN;   // [d][s]

    bf16x8 Qf[2][2];
#pragma unroll
    for (int sub = 0; sub < 2; ++sub)
#pragma unroll
        for (int c = 0; c < 2; ++c)
            Qf[sub][c] = *(const bf16x8*)
                &Q[((size_t)bh * S_LEN + q0 + sub * 16 + l16) * DK +
                   c * 32 + quad * 8];

    float l_i[2] = { 0.0f, 0.0f };
    f32x4 o[2][4] = {};

    const int ntiles = (bx >> 1) + 1;
    const int t0 = wave;

    bf16x8 Kf[4][2], Vf[4][2];
    if (t0 < ntiles) {
        const int k0 = t0 * 64;
#pragma unroll
        for (int kt = 0; kt < 4; ++kt)
#pragma unroll
            for (int c = 0; c < 2; ++c)
                Kf[kt][c] = *(const bf16x8*)
                    &Kb[(size_t)(k0 + kt * 16 + l16) * DK + c * 32 + quad * 8];
#pragma unroll
        for (int dt = 0; dt < 4; ++dt)
#pragma unroll
            for (int c = 0; c < 2; ++c)
                Vf[dt][c] = *(const bf16x8*)
                    &Vtb[(size_t)(dt * 16 + l16) * S_LEN + k0 + c * 32 + quad * 8];
    }

    for (int t = t0; t < ntiles; t += 4) {
        const int k0 = t * 64;
        const bool pn = (t + 4) < ntiles;
        const int k0n = k0 + 256;

        // ---- S^T + softmax + P store (consumes Kf) ----
#pragma unroll
        for (int sub = 0; sub < 2; ++sub) {
            f32x4 sT[4] = {};
#pragma unroll
            for (int c = 0; c < 2; ++c)
#pragma unroll
                for (int kt = 0; kt < 4; ++kt)
                    sT[kt] = __builtin_amdgcn_mfma_f32_16x16x32_bf16(
                        Kf[kt][c], Qf[sub][c], sT[kt], 0, 0, 0);

            const int qg = q0 + sub * 16 + l16;
            if (k0 + 63 > q0 + sub * 16) {   // causal mask (edge tiles only)
#pragma unroll
                for (int kt = 0; kt < 4; ++kt)
#pragma unroll
                    for (int r = 0; r < 4; ++r)
                        if (k0 + kt * 16 + quad * 4 + r > qg)
                            sT[kt][r] = -1e30f;
            }

            float rs = 0.0f;
            const int prow = wave * 32 + sub * 16 + l16;
#pragma unroll
            for (int kt = 0; kt < 4; ++kt) {
                float p0 = exp2f(sT[kt][0]);
                float p1 = exp2f(sT[kt][1]);
                float p2 = exp2f(sT[kt][2]);
                float p3 = exp2f(sT[kt][3]);
                rs += (p0 + p1) + (p2 + p3);
                short4v pk;
                pk.x = f2bf(p0); pk.y = f2bf(p1);
                pk.z = f2bf(p2); pk.w = f2bf(p3);
                *(short4v*)&Ps[prow][kt * 16 + quad * 4] = pk;
            }
            rs += __shfl_xor(rs, 16);
            rs += __shfl_xor(rs, 32);
            l_i[sub] += rs;
        }

        // ---- K prefetch for t+4 into Kf (after last Kf use) ----
        if (pn) {
#pragma unroll
            for (int kt = 0; kt < 4; ++kt)
#pragma unroll
                for (int c = 0; c < 2; ++c)
                    Kf[kt][c] = *(const bf16x8*)
                        &Kb[(size_t)(k0n + kt * 16 + l16) * DK + c * 32 + quad * 8];
        }

        // ---- O^T += V^T P^T (consumes Vf; Ps wave-private) ----
        bf16x8 Pf[2][2];
#pragma unroll
        for (int sub = 0; sub < 2; ++sub)
#pragma unroll
            for (int c = 0; c < 2; ++c)
                Pf[sub][c] = *(const bf16x8*)
                    &Ps[wave * 32 + sub * 16 + l16][c * 32 + quad * 8];
#pragma unroll
        for (int c = 0; c < 2; ++c)
#pragma unroll
            for (int dt = 0; dt < 4; ++dt)
#pragma unroll
                for (int sub = 0; sub < 2; ++sub)
                    o[sub][dt] = __builtin_amdgcn_mfma_f32_16x16x32_bf16(
                        Vf[dt][c], Pf[sub][c], o[sub][dt], 0, 0, 0);

        // ---- V prefetch for t+4 into Vf (after last Vf use) ----
        if (pn) {
#pragma unroll
            for (int dt = 0; dt < 4; ++dt)
#pragma unroll
                for (int c = 0; c < 2; ++c)
                    Vf[dt][c] = *(const bf16x8*)
                        &Vtb[(size_t)(dt * 16 + l16) * S_LEN + k0n + c * 32 + quad * 8];
        }
    }

    // ---- combine: Ps region is dead; reuse as Ob/lb (barrier-guarded) ----
    __syncthreads();
#pragma unroll
    for (int sub = 0; sub < 2; ++sub)
#pragma unroll
        for (int dt = 0; dt < 4; ++dt)
#pragma unroll
            for (int r = 0; r < 4; ++r)
                Ob[wave][sub * 16 + l16][dt * 16 + quad * 4 + r] = o[sub][dt][r];
    if (quad == 0) {
        lb[wave * 32 + l16]      = l_i[0];
        lb[wave * 32 + 16 + l16] = l_i[1];
    }
    __syncthreads();

    const int q = tid >> 3;
    const int d0 = (tid & 7) * 8;
    float l = lb[q] + lb[32 + q] + lb[64 + q] + lb[96 + q];
    float linv = 1.0f / l;
    float s[8];
#pragma unroll
    for (int j = 0; j < 8; ++j)
        s[j] = Ob[0][q][d0 + j] + Ob[1][q][d0 + j] +
               Ob[2][q][d0 + j] + Ob[3][q][d0 + j];
    const int bi = bh >> 4;
    const int head = bh & 15;
    short h[8];
#pragma unroll
    for (int j = 0; j < 8; ++j) h[j] = f2bf(s[j] * linv);
    *(bf16x8*)&O[((size_t)bi * S_LEN + q0 + q) * D_MODEL + head * DK + d0] =
        *(bf16x8*)h;
}

extern "C" void kernel_launch(void* const* d_in, const int* in_sizes, int n_in,
                              void* d_out, int out_size, void* d_ws, size_t ws_size,
                              hipStream_t stream) {
    const float* x  = (const float*)d_in[0];
    const float* Wq = (const float*)d_in[1];
    const float* Wk = (const float*)d_in[2];
    const float* Wv = (const float*)d_in[3];
    const float* Wo = (const float*)d_in[4];
    const int*   tp = (const int*)d_in[5];
    float* out = (float*)d_out;

    const int n  = BATCH * S_LEN * D_MODEL;       // 8388608
    const int nw = D_MODEL * D_MODEL;             // 1048576
    short* sw   = (short*)d_ws;
    short* xbf  = sw;
    short* Qbf  = sw + (size_t)n;
    short* Kbf  = sw + (size_t)2 * n;
    short* Vtbf = sw + (size_t)3 * n;             // V^T (b*NH*DK, S)
    short* Obf  = sw + (size_t)4 * n;
    short* Wqkv = sw + (size_t)5 * n;             // Wq,Wk,Wv,Wo stacked

    dim3 blk(256);
    conv_bf16<<<n / (256 * 8), blk, 0, stream>>>(x, xbf, n);
    dim3 gw(nw / (256 * 8), 4);
    conv_w4<<<gw, blk, 0, stream>>>(Wq, Wk, Wv, Wo, Wqkv);

    dim3 gqkv(24, (BATCH * S_LEN) / 128);               // (24, 64)
    proj_qkv<<<gqkv, blk, 0, stream>>>(xbf, Wqkv, tp, Qbf, Kbf, Vtbf);

    dim3 gattn(S_LEN / 32, BATCH * NH);                 // (64, 64)
    attn_bf16<<<gattn, blk, 0, stream>>>(Qbf, Kbf, Vtbf, Obf);

    dim3 gout(D_MODEL / 128, (BATCH * S_LEN) / 128);    // (8, 64)
    proj_out<<<gout, blk, 0, stream>>>(Obf, Wqkv + (size_t)3 * nw, out);
}